// Round 19
// baseline (130.214 us; speedup 1.0000x reference)
//
#include <hip/hip_runtime.h>
#include <math.h>

#define BB 2
#define SS 2048
#define HH 1024
#define NH 16
#define HD 64
#define MM (BB*SS)   // 4096

typedef __attribute__((ext_vector_type(8))) _Float16 f16x8;
typedef __attribute__((ext_vector_type(2))) __fp16 hf16x2;
typedef __attribute__((ext_vector_type(4))) float f32x4;
typedef __attribute__((ext_vector_type(16))) float f32x16;

// 0.125 (1/sqrt(64)) * log2(e), folded into Q at the projection epilogue
#define QSCALE 0.18033688011112042f

__device__ __forceinline__ unsigned short f2h(float f) {
    union { _Float16 h; unsigned short u; } c;
    c.h = (_Float16)f;
    return c.u;
}

// pack two floats to fp16x2 (RTZ) -> raw u32
__device__ __forceinline__ unsigned int pkh(float a, float b) {
    union { hf16x2 h; unsigned int u; } c;
    c.h = __builtin_amdgcn_cvt_pkrtz(a, b);
    return c.u;
}

__device__ __forceinline__ void gld16(const void* g, void* s) {
    __builtin_amdgcn_global_load_lds(
        (const __attribute__((address_space(1))) void*)g,
        (__attribute__((address_space(3))) void*)s, 16, 0, 0);
}

// ---------------- prep: cast x/W to fp16 + RoPE/mask tables + mask flags ----------------
__global__ __launch_bounds__(256) void prep(
    const float* __restrict__ x, const float* __restrict__ mask,
    const float* __restrict__ Wq, const float* __restrict__ Wk,
    const float* __restrict__ Wv, const float* __restrict__ Wo,
    unsigned short* __restrict__ xf, unsigned short* __restrict__ wf,
    float* __restrict__ ctab, float* __restrict__ stab, float* __restrict__ mt,
    unsigned int* __restrict__ mflag)
{
    int gtid = blockIdx.x * 256 + threadIdx.x;      // 2048*256 = 524288 threads
    if (gtid < SS * 32) {                            // RoPE table, f64 trig
        int s = gtid >> 5, i = gtid & 31;
        double invf = pow(10000.0, -(double)i / 32.0);
        double a = (double)s * invf;
        ctab[gtid] = (float)cos(a);
        stab[gtid] = (float)sin(a);
    }
    if (gtid < BB * SS) {                            // additive mask table (exp2 domain)
        float mv = mask[gtid];
        mt[gtid] = (1.0f - mv) * (-1.0e38f);
        unsigned long long bal = __ballot(mv == 1.0f);
        if ((threadIdx.x & 63) == 0)
            mflag[gtid >> 6] = (bal == ~0ull) ? 1u : 0u;
    }
    for (int it = gtid; it < 2097152; it += 524288) {   // 2M float4 items
        float4 v; unsigned short* d; size_t off;
        if (it < 1048576) {                              // x: [4096][1024]
            off = (size_t)it * 4;
            v = *(const float4*)(x + off);
            d = xf;
        } else {                                         // W concat rows: Wq,Wk,Wv,Wo
            off = (size_t)(it - 1048576) * 4;
            int row = (int)(off >> 10);
            const float* W = row < 1024 ? Wq : row < 2048 ? Wk : row < 3072 ? Wv : Wo;
            v = *(const float4*)(W + (((size_t)(row & 1023)) << 10) + (off & 1023));
            d = wf;
        }
        *(ushort4*)(d + off) = make_ushort4(f2h(v.x), f2h(v.y), f2h(v.z), f2h(v.w));
    }
}

// ---------------- fp16 MFMA GEMM (128x128 tile, BK=32, dbuf 32KB) ----------------
// (unchanged — verified 0 conflicts, 2-phase dbuf; k swizzled, v^T swizzled)
template<int MODE>
__global__ __launch_bounds__(256, 3) void gemm3(
    const unsigned short* __restrict__ Axf,
    const unsigned short* __restrict__ Wf,
    const float* __restrict__ ctab, const float* __restrict__ stab,
    unsigned short* __restrict__ qo, unsigned short* __restrict__ ko,
    unsigned short* __restrict__ vo, float* __restrict__ fout)
{
    __shared__ __align__(16) short lsA[2][128*32];
    __shared__ __align__(16) short lsB[2][128*32];

    const int t = threadIdx.x;
    const int m0 = blockIdx.x * 128;
    const int brow0 = (MODE == 0 ? 0 : 3072) + blockIdx.y * 128;
    const int lane = t & 63, wv = t >> 6;
    const int wm = (wv >> 1) * 64, wn = (wv & 1) * 64;
    const int fr = lane & 15, fg = lane >> 4;

    const int srow = t >> 2, pc = t & 3;
    const int scx = (pc ^ ((srow >> 1) & 3)) * 8;     // source col offset (shorts)
    const int lo  = srow * 32 + pc * 8;               // physical dest (shorts)
    const size_t gA0 = (size_t)(m0 + srow) * HH + scx;
    const size_t gA1 = (size_t)(m0 + 64 + srow) * HH + scx;
    const size_t gB0 = (size_t)(brow0 + srow) * HH + scx;
    const size_t gB1 = (size_t)(brow0 + 64 + srow) * HH + scx;

    f32x4 acc[4][4] = {};

#define STAGE(sel, kk) do { \
        gld16(Axf + gA0 + (kk), &lsA[sel][lo]);            \
        gld16(Wf  + gB0 + (kk), &lsB[sel][lo]);            \
        gld16(Axf + gA1 + (kk), &lsA[sel][lo + 64*32]);    \
        gld16(Wf  + gB1 + (kk), &lsB[sel][lo + 64*32]);    \
    } while (0)

    STAGE(0, 0);
    __syncthreads();

    int cur = 0;
    for (int k0 = 0; k0 < HH; k0 += 32) {
        if (k0 + 32 < HH) STAGE(cur ^ 1, k0 + 32);

        f16x8 ah[4], bh[4];
        const int swz = (fg ^ ((fr >> 1) & 3)) * 8;   // swizzled read granule
        #pragma unroll
        for (int mi = 0; mi < 4; ++mi)
            ah[mi] = *(const f16x8*)&lsA[cur][(wm + 16*mi + fr)*32 + swz];
        #pragma unroll
        for (int ni = 0; ni < 4; ++ni)
            bh[ni] = *(const f16x8*)&lsB[cur][(wn + 16*ni + fr)*32 + swz];

        __builtin_amdgcn_s_setprio(1);
        #pragma unroll
        for (int mi = 0; mi < 4; ++mi)
            #pragma unroll
            for (int ni = 0; ni < 4; ++ni)
                acc[mi][ni] = __builtin_amdgcn_mfma_f32_16x16x32_f16(ah[mi], bh[ni], acc[mi][ni], 0, 0, 0);
        __builtin_amdgcn_s_setprio(0);
        __syncthreads();
        cur ^= 1;
    }
#undef STAGE

    if (MODE == 0) {
        const int mat = brow0 >> 10;                 // 0=Q 1=K 2=V
        const int obase = (brow0 & 1023) + wn;       // 64-aligned
        const int h = obase >> 6;
        #pragma unroll
        for (int mi = 0; mi < 4; ++mi)
            #pragma unroll
            for (int rr = 0; rr < 4; ++rr) {
                int m = m0 + wm + 16*mi + 4*fg + rr;
                int b = m >> 11, s = m & (SS - 1);
                float v[4];
                #pragma unroll
                for (int ni = 0; ni < 4; ++ni) v[ni] = acc[mi][ni][rr];
                if (mat < 2) {                        // RoPE on Q,K
                    #pragma unroll
                    for (int ni = 0; ni < 2; ++ni) {
                        int i = 16*ni + fr;
                        float c = ctab[s*32 + i], sn = stab[s*32 + i];
                        float v1 = v[ni], v2 = v[ni + 2];
                        v[ni]     = v1*c - v2*sn;
                        v[ni + 2] = v2*c + v1*sn;
                    }
                }
                if (mat == 0) {                       // fold softmax scale into Q
                    #pragma unroll
                    for (int ni = 0; ni < 4; ++ni) v[ni] *= QSCALE;
                }
                size_t base = ((size_t)(b*NH + h) * SS + s) * HD;
                #pragma unroll
                for (int ni = 0; ni < 4; ++ni) {
                    int d = 16*ni + fr;
                    unsigned short hb = f2h(v[ni]);
                    if (mat == 0)      qo[base + d] = hb;
                    else if (mat == 1) ko[base + (d ^ ((s & 7) << 3))] = hb;
                    else {
                        size_t va = ((size_t)(b*NH + h) * HD + d) * SS
                                  + (s & ~63) + ((s & 63) ^ ((d & 7) << 3));
                        vo[va] = hb;
                    }
                }
            }
    } else {
        const int n0 = blockIdx.y * 128 + wn;
        #pragma unroll
        for (int mi = 0; mi < 4; ++mi)
            #pragma unroll
            for (int rr = 0; rr < 4; ++rr) {
                int m = m0 + wm + 16*mi + 4*fg + rr;
                #pragma unroll
                for (int ni = 0; ni < 4; ++ni)
                    fout[(size_t)m * HH + n0 + 16*ni + fr] = acc[mi][ni][rr];
            }
    }
}

// ---------------- flash attention: k-split waves, 3-ring, FIXED barrier order ----------------
// r18 RACE FIX: with a 3-ring, stage(kt+2) targets buffer (kt+2)%3 == (kt-1)%3.
// r18 issued the stage BEFORE the iteration barrier, racing laggards still in
// COMPUTE(kt-1). Now the order is [vmcnt; s_barrier; STAGE(kt+2); COMPUTE(kt)]:
// the barrier proves all waves finished COMPUTE(kt-1) before any DMA touches
// its buffer, and the next write to buffer kt%3 (stage kt+3) is gated by
// barrier kt+1 which proves COMPUTE(kt) reads are done. Counted vmcnt: steady
// state outstanding = stage(kt)+stage(kt+1) = 8 -> vmcnt(4) waits exactly for
// stage(kt); vmcnt(0) at the last tile. Pre-loop qa/fmask VMEM explicitly
// drained so in-loop counts see staging ops only.
__global__ __launch_bounds__(256, 3) void attn(
    const unsigned short* __restrict__ qg, const unsigned short* __restrict__ kg,
    const unsigned short* __restrict__ vtg, const float* __restrict__ mt,
    const unsigned int* __restrict__ mfl, unsigned short* __restrict__ cf)
{
    __shared__ __align__(16) short Ks[3][64*64];
    __shared__ __align__(16) short Vs[3][64*64];

    const int t = threadIdx.x, lane = t & 63, wv = t >> 6;   // wv 0..3
    const int ql = lane & 31;            // q (col) / A-frag row index
    const int u  = lane >> 5;            // lane half
    const int qx = ql & 7;               // swizzle bits
    const int qh = wv & 1, kh = wv >> 1;
    const int flat = blockIdx.x;
    const int bh = (flat & 7) + ((flat >> 8) << 3);          // XCD-grouped
    const int q0 = ((flat >> 3) & 31) * 64;
    const int b = bh >> 4, h = bh & 15;

    const unsigned short* kgb = kg  + (size_t)bh*SS*HD;
    const unsigned short* vgb = vtg + (size_t)bh*HD*SS;
    const float* mtb = mt + (size_t)b*SS;
    const unsigned int* mfb = mfl + b*32;

    // hoist mask flags into a bitmask BEFORE the loop
    unsigned int fmask = 0;
    for (int i = 0; i < 32; ++i) fmask |= (mfb[i] & 1u) << i;

    // Q B-frags: q-row = q0+32qh+ql, d = 16dc + 8u + {0..7} (QSCALE folded)
    f16x8 qa[4];
    #pragma unroll
    for (int dc = 0; dc < 4; ++dc)
        qa[dc] = *(const f16x8*)&qg[((size_t)bh*SS + q0 + 32*qh + ql)*HD + 16*dc + 8*u];

    f16x8 onev;
    #pragma unroll
    for (int i = 0; i < 8; ++i) onev[i] = (_Float16)1.0f;

    f32x16 o[2] = {};                    // k-partial O^T d-tiles for q=ql
    f32x16 oS = {};                      // ones-MFMA row-sum accumulator

    const int srow = t >> 3, sg = t & 7;   // staging: 32 rows x 8 granules (x2)

    // drain ALL pre-loop VMEM/SMEM so in-loop vmcnt counting is exact
    __builtin_amdgcn_sched_barrier(0);
    asm volatile("s_waitcnt vmcnt(0) lgkmcnt(0)" ::: "memory");
    __builtin_amdgcn_sched_barrier(0);

#define STAGEKV(kt_, bi_) do { \
        const int kn_ = (kt_) * 64; \
        gld16(kgb + (size_t)(kn_+srow)*HD + sg*8,      &Ks[bi_][srow*64 + sg*8]); \
        gld16(kgb + (size_t)(kn_+32+srow)*HD + sg*8,   &Ks[bi_][(32+srow)*64 + sg*8]); \
        gld16(vgb + (size_t)srow*SS + kn_ + sg*8,      &Vs[bi_][srow*64 + sg*8]); \
        gld16(vgb + (size_t)(32+srow)*SS + kn_ + sg*8, &Vs[bi_][(32+srow)*64 + sg*8]); \
    } while (0)

    STAGEKV(0, 0);
    STAGEKV(1, 1);

    for (int kt = 0; kt < SS/64; ++kt) {
        const int bi = kt % 3;
        __builtin_amdgcn_sched_barrier(0);
        if (kt + 1 < SS/64) {
            asm volatile("s_waitcnt vmcnt(4)" ::: "memory");   // own stage(kt) done
        } else {
            asm volatile("s_waitcnt vmcnt(0)" ::: "memory");
        }
        __builtin_amdgcn_s_barrier();      // all waves' stage(kt) complete;
        __builtin_amdgcn_sched_barrier(0); // all waves done reading tile kt-1

        if (kt + 2 < SS/64) STAGEKV(kt + 2, (kt + 2) % 3);   // -> buffer (kt-1)%3, now free

        // K A-frags for this wave's 32-k slice; QK^T: sc = S^T[32kh+row][q]
        f16x8 kb[4];
        #pragma unroll
        for (int dc = 0; dc < 4; ++dc)
            kb[dc] = *(const f16x8*)&Ks[bi][(32*kh + ql)*64 + ((2*dc + u) ^ qx)*8];

        f32x16 sc = {};
        __builtin_amdgcn_s_setprio(1);
        #pragma unroll
        for (int dc = 0; dc < 4; ++dc)
            sc = __builtin_amdgcn_mfma_f32_32x32x16_f16(kb[dc], qa[dc], sc, 0, 0, 0);
        __builtin_amdgcn_s_setprio(0);

        // V A-frags (own k-slice only)
        f16x8 vb[2][2];
        #pragma unroll
        for (int dt = 0; dt < 2; ++dt)
            #pragma unroll
            for (int ki = 0; ki < 2; ++ki)
                vb[dt][ki] = *(const f16x8*)&Vs[bi][(32*dt + ql)*64 + ((4*kh + 2*ki + u) ^ qx)*8];

        // P = 2^(s [+ madd])  (row-sum comes from ones-MFMA below)
        if ((fmask >> kt) & 1) {
            #pragma unroll
            for (int r = 0; r < 16; ++r)
                sc[r] = __builtin_amdgcn_exp2f(sc[r]);
        } else {
            #pragma unroll
            for (int g = 0; g < 4; ++g) {
                float4 m4 = *(const float4*)&mtb[kt*64 + 32*kh + 8*g + 4*u];
                #pragma unroll
                for (int j = 0; j < 4; ++j)
                    sc[4*g + j] = __builtin_amdgcn_exp2f(sc[4*g + j] + (&m4.x)[j]);
            }
        }

        // PV: per 16-k chunk build P B-frag via cvt_pk + permlane32_swap
        __builtin_amdgcn_s_setprio(1);
        #pragma unroll
        for (int ki = 0; ki < 2; ++ki) {
            const int R0 = 8 * ki;
            unsigned int A0 = pkh(sc[R0+0], sc[R0+1]);
            unsigned int A1 = pkh(sc[R0+2], sc[R0+3]);
            unsigned int B0 = pkh(sc[R0+4], sc[R0+5]);
            unsigned int B1 = pkh(sc[R0+6], sc[R0+7]);
            asm volatile("v_permlane32_swap_b32 %0, %1" : "+v"(A0), "+v"(B0));
            asm volatile("v_permlane32_swap_b32 %0, %1" : "+v"(A1), "+v"(B1));
            union { unsigned int w[4]; f16x8 v; } pf;
            pf.w[0] = A0; pf.w[1] = A1; pf.w[2] = B0; pf.w[3] = B1;
            o[0] = __builtin_amdgcn_mfma_f32_32x32x16_f16(vb[0][ki], pf.v, o[0], 0, 0, 0);
            o[1] = __builtin_amdgcn_mfma_f32_32x32x16_f16(vb[1][ki], pf.v, o[1], 0, 0, 0);
            oS   = __builtin_amdgcn_mfma_f32_32x32x16_f16(onev,     pf.v, oS,   0, 0, 0);
        }
        __builtin_amdgcn_s_setprio(0);
    }
#undef STAGEKV

    // ---- epilogue: cross-kh combine through ring-buffer-as-f32-scratch ----
    // tile 31 read buffer 1; laggards can touch only Ks[1]/Vs[1] — scratch in
    // Ks[0]/Vs[0] is disjoint; __syncthreads orders writer/reader phases.
    float lpart = oS[0];                 // full-slice row-sum (all oS rows equal)
    float* lscr = (float*)Vs;            // 128 floats  (Vs[0])
    float* oscr = (float*)Ks;            // 2048 floats (Ks[0], k-major: conflict-free)
    if (kh == 1) lscr[qh*64 + lane] = lpart;
    __syncthreads();
    float inv = 0.f;
    if (kh == 0)
        inv = 1.0f / (lpart + lscr[qh*64 + lane]);
    const size_t base = ((size_t)b*SS + q0 + 32*qh + ql)*HH + h*HD;
    #pragma unroll
    for (int dt = 0; dt < 2; ++dt) {
        __syncthreads();
        if (kh == 1) {
            #pragma unroll
            for (int r = 0; r < 16; ++r)
                oscr[r*128 + qh*64 + lane] = o[dt][r];
        }
        __syncthreads();
        if (kh == 0) {
            #pragma unroll
            for (int g = 0; g < 4; ++g) {
                float v0 = (o[dt][4*g+0] + oscr[(4*g+0)*128 + qh*64 + lane]) * inv;
                float v1 = (o[dt][4*g+1] + oscr[(4*g+1)*128 + qh*64 + lane]) * inv;
                float v2 = (o[dt][4*g+2] + oscr[(4*g+2)*128 + qh*64 + lane]) * inv;
                float v3 = (o[dt][4*g+3] + oscr[(4*g+3)*128 + qh*64 + lane]) * inv;
                uint2 w; w.x = pkh(v0, v1); w.y = pkh(v2, v3);
                *(uint2*)&cf[base + 32*dt + 8*g + 4*u] = w;
            }
        }
    }
}

extern "C" void kernel_launch(void* const* d_in, const int* in_sizes, int n_in,
                              void* d_out, int out_size, void* d_ws, size_t ws_size,
                              hipStream_t stream) {
    const float* x    = (const float*)d_in[0];
    const float* mask = (const float*)d_in[1];
    const float* Wq   = (const float*)d_in[2];
    const float* Wk   = (const float*)d_in[3];
    const float* Wv   = (const float*)d_in[4];
    const float* Wo   = (const float*)d_in[5];
    float* out = (float*)d_out;

    const size_t T = (size_t)MM * HH;            // 4M elements
    unsigned short* xf = (unsigned short*)d_ws;  // 8MB each
    unsigned short* wf = xf + T;                 // [4096][1024]: Wq,Wk,Wv,Wo rows
    unsigned short* qt = wf + T;
    unsigned short* kt = qt + T;
    unsigned short* vt = kt + T;
    float* ctab = (float*)(vt + T);
    float* stab = ctab + SS*32;
    float* mt   = stab + SS*32;                  // additive mask table [BB][SS]
    unsigned int* mfg = (unsigned int*)(mt + BB*SS);   // [BB][32] all-ones flags
    unsigned short* cf = xf;                     // ctx aliases xf (x consumed)

    prep<<<2048, 256, 0, stream>>>(x, mask, Wq, Wk, Wv, Wo, xf, wf, ctab, stab, mt, mfg);
    gemm3<0><<<dim3(MM/128, 3*HH/128), 256, 0, stream>>>(xf, wf, ctab, stab,
                                                         qt, kt, vt, nullptr);
    attn<<<1024, 256, 0, stream>>>(qt, kt, vt, mt, mfg, cf);
    gemm3<1><<<dim3(MM/128, HH/128), 256, 0, stream>>>(cf, wf, nullptr, nullptr,
                                                       nullptr, nullptr, nullptr, out);
}

// Round 20
// 116.499 us; speedup vs baseline: 1.1177x; 1.1177x over previous
//
#include <hip/hip_runtime.h>
#include <math.h>

#define BB 2
#define SS 2048
#define HH 1024
#define NH 16
#define HD 64
#define MM (BB*SS)   // 4096

typedef __attribute__((ext_vector_type(8))) _Float16 f16x8;
typedef __attribute__((ext_vector_type(2))) __fp16 hf16x2;
typedef __attribute__((ext_vector_type(4))) float f32x4;

// 0.125 (1/sqrt(64)) * log2(e), folded into Q at the projection epilogue
#define QSCALE 0.18033688011112042f

__device__ __forceinline__ unsigned short f2h(float f) {
    union { _Float16 h; unsigned short u; } c;
    c.h = (_Float16)f;
    return c.u;
}

// pack two floats to fp16x2 (RTZ) -> raw u32
__device__ __forceinline__ unsigned int pkh(float a, float b) {
    union { hf16x2 h; unsigned int u; } c;
    c.h = __builtin_amdgcn_cvt_pkrtz(a, b);
    return c.u;
}

__device__ __forceinline__ void gld16(const void* g, void* s) {
    __builtin_amdgcn_global_load_lds(
        (const __attribute__((address_space(1))) void*)g,
        (__attribute__((address_space(3))) void*)s, 16, 0, 0);
}

// ---------------- prep: cast x/W to fp16 + RoPE/mask tables + mask flags ----------------
__global__ __launch_bounds__(256) void prep(
    const float* __restrict__ x, const float* __restrict__ mask,
    const float* __restrict__ Wq, const float* __restrict__ Wk,
    const float* __restrict__ Wv, const float* __restrict__ Wo,
    unsigned short* __restrict__ xf, unsigned short* __restrict__ wf,
    float* __restrict__ ctab, float* __restrict__ stab, float* __restrict__ mt,
    unsigned int* __restrict__ mflag)
{
    int gtid = blockIdx.x * 256 + threadIdx.x;      // 2048*256 = 524288 threads
    if (gtid < SS * 32) {                            // RoPE table, f64 trig
        int s = gtid >> 5, i = gtid & 31;
        double invf = pow(10000.0, -(double)i / 32.0);
        double a = (double)s * invf;
        ctab[gtid] = (float)cos(a);
        stab[gtid] = (float)sin(a);
    }
    if (gtid < BB * SS) {                            // additive mask table (exp2 domain)
        float mv = mask[gtid];
        mt[gtid] = (1.0f - mv) * (-1.0e38f);
        // per-(b, 64k-tile) all-ones flag: one ballot per wave, lane0 stores
        unsigned long long bal = __ballot(mv == 1.0f);
        if ((threadIdx.x & 63) == 0)
            mflag[gtid >> 6] = (bal == ~0ull) ? 1u : 0u;
    }
    for (int it = gtid; it < 2097152; it += 524288) {   // 2M float4 items
        float4 v; unsigned short* d; size_t off;
        if (it < 1048576) {                              // x: [4096][1024]
            off = (size_t)it * 4;
            v = *(const float4*)(x + off);
            d = xf;
        } else {                                         // W concat rows: Wq,Wk,Wv,Wo
            off = (size_t)(it - 1048576) * 4;
            int row = (int)(off >> 10);
            const float* W = row < 1024 ? Wq : row < 2048 ? Wk : row < 3072 ? Wv : Wo;
            v = *(const float4*)(W + (((size_t)(row & 1023)) << 10) + (off & 1023));
            d = wf;
        }
        *(ushort4*)(d + off) = make_ushort4(f2h(v.x), f2h(v.y), f2h(v.z), f2h(v.w));
    }
}

// ---------------- fp16 MFMA GEMM (128x128 tile, BK=32, 3-ring 48KB) ----------------
// LDS tiles [128 rows][4 granules of 16B], 2-bit XOR swizzle (round-5, verified
// 0 conflicts). NEW (r20): counted-vmcnt 3-buffer ring — the r19-verified
// ordering [vmcnt(4); s_barrier; STAGE(kt+2 -> (kt+2)%3); compute(kt)].
// The barrier proves all waves finished compute(kt-1) before the stage DMA
// touches buffer (kt-1)%3; vmcnt(4) waits exactly for own stage(kt) (steady
// outstanding = stage(kt)+stage(kt+1) = 8 gld16). No full vmcnt(0) drain in
// the loop (the documented ~20% m97 barrier stall). Loop has no other VMEM.
// Occupancy unchanged: 48KB x 3 blocks = 144KB <= 160KB.
template<int MODE>
__global__ __launch_bounds__(256, 3) void gemm3(
    const unsigned short* __restrict__ Axf,
    const unsigned short* __restrict__ Wf,
    const float* __restrict__ ctab, const float* __restrict__ stab,
    unsigned short* __restrict__ qo, unsigned short* __restrict__ ko,
    unsigned short* __restrict__ vo, float* __restrict__ fout)
{
    __shared__ __align__(16) short lsA[3][128*32];
    __shared__ __align__(16) short lsB[3][128*32];

    const int t = threadIdx.x;
    const int m0 = blockIdx.x * 128;
    const int brow0 = (MODE == 0 ? 0 : 3072) + blockIdx.y * 128;
    const int lane = t & 63, wv = t >> 6;
    const int wm = (wv >> 1) * 64, wn = (wv & 1) * 64;
    const int fr = lane & 15, fg = lane >> 4;

    const int srow = t >> 2, pc = t & 3;
    const int scx = (pc ^ ((srow >> 1) & 3)) * 8;     // source col offset (shorts)
    const int lo  = srow * 32 + pc * 8;               // physical dest (shorts)
    const size_t gA0 = (size_t)(m0 + srow) * HH + scx;
    const size_t gA1 = (size_t)(m0 + 64 + srow) * HH + scx;
    const size_t gB0 = (size_t)(brow0 + srow) * HH + scx;
    const size_t gB1 = (size_t)(brow0 + 64 + srow) * HH + scx;

    f32x4 acc[4][4] = {};

#define STAGE(sel, kk) do { \
        gld16(Axf + gA0 + (kk), &lsA[sel][lo]);            \
        gld16(Wf  + gB0 + (kk), &lsB[sel][lo]);            \
        gld16(Axf + gA1 + (kk), &lsA[sel][lo + 64*32]);    \
        gld16(Wf  + gB1 + (kk), &lsB[sel][lo + 64*32]);    \
    } while (0)

    STAGE(0, 0);
    STAGE(1, 32);

    for (int kt = 0; kt < HH/32; ++kt) {
        const int bi = kt % 3;
        __builtin_amdgcn_sched_barrier(0);
        if (kt + 1 < HH/32) {
            asm volatile("s_waitcnt vmcnt(4)" ::: "memory");   // own stage(kt) done
        } else {
            asm volatile("s_waitcnt vmcnt(0)" ::: "memory");
        }
        __builtin_amdgcn_s_barrier();      // all waves' stage(kt) complete;
        __builtin_amdgcn_sched_barrier(0); // all waves done reading tile kt-1

        if (kt + 2 < HH/32) STAGE((kt + 2) % 3, (kt + 2) * 32);  // buf (kt-1)%3, now free

        f16x8 ah[4], bh[4];
        const int swz = (fg ^ ((fr >> 1) & 3)) * 8;   // swizzled read granule
        #pragma unroll
        for (int mi = 0; mi < 4; ++mi)
            ah[mi] = *(const f16x8*)&lsA[bi][(wm + 16*mi + fr)*32 + swz];
        #pragma unroll
        for (int ni = 0; ni < 4; ++ni)
            bh[ni] = *(const f16x8*)&lsB[bi][(wn + 16*ni + fr)*32 + swz];

        __builtin_amdgcn_s_setprio(1);
        #pragma unroll
        for (int mi = 0; mi < 4; ++mi)
            #pragma unroll
            for (int ni = 0; ni < 4; ++ni)
                acc[mi][ni] = __builtin_amdgcn_mfma_f32_16x16x32_f16(ah[mi], bh[ni], acc[mi][ni], 0, 0, 0);
        __builtin_amdgcn_s_setprio(0);
    }
#undef STAGE

    if (MODE == 0) {
        const int mat = brow0 >> 10;                 // 0=Q 1=K 2=V
        const int obase = (brow0 & 1023) + wn;       // 64-aligned
        const int h = obase >> 6;
        #pragma unroll
        for (int mi = 0; mi < 4; ++mi)
            #pragma unroll
            for (int rr = 0; rr < 4; ++rr) {
                int m = m0 + wm + 16*mi + 4*fg + rr;
                int b = m >> 11, s = m & (SS - 1);
                float v[4];
                #pragma unroll
                for (int ni = 0; ni < 4; ++ni) v[ni] = acc[mi][ni][rr];
                if (mat < 2) {                        // RoPE on Q,K
                    #pragma unroll
                    for (int ni = 0; ni < 2; ++ni) {
                        int i = 16*ni + fr;
                        float c = ctab[s*32 + i], sn = stab[s*32 + i];
                        float v1 = v[ni], v2 = v[ni + 2];
                        v[ni]     = v1*c - v2*sn;
                        v[ni + 2] = v2*c + v1*sn;
                    }
                }
                if (mat == 0) {                       // fold softmax scale into Q
                    #pragma unroll
                    for (int ni = 0; ni < 4; ++ni) v[ni] *= QSCALE;
                }
                size_t base = ((size_t)(b*NH + h) * SS + s) * HD;
                #pragma unroll
                for (int ni = 0; ni < 4; ++ni) {
                    int d = 16*ni + fr;
                    unsigned short hb = f2h(v[ni]);
                    if (mat == 0)      qo[base + d] = hb;
                    else if (mat == 1) ko[base + (d ^ ((s & 7) << 3))] = hb;
                    else {
                        size_t va = ((size_t)(b*NH + h) * HD + d) * SS
                                  + (s & ~63) + ((s & 63) ^ ((d & 7) << 3));
                        vo[va] = hb;
                    }
                }
            }
    } else {
        const int n0 = blockIdx.y * 128 + wn;
        #pragma unroll
        for (int mi = 0; mi < 4; ++mi)
            #pragma unroll
            for (int rr = 0; rr < 4; ++rr) {
                int m = m0 + wm + 16*mi + 4*fg + rr;
                #pragma unroll
                for (int ni = 0; ni < 4; ++ni)
                    fout[(size_t)m * HH + n0 + 16*ni + fr] = acc[mi][ni][rr];
            }
    }
}

// ---------------- flash attention, swapped-operand form (r16 exact, 49.6us) ----------------
// 1-D grid 512, XCD-swizzled (K/V L2 locality: FETCH 69.7->12.3MB, round 9).
// S^T = mfma(K,Q); O^T = mfma(V^T,P); row-sum via ones-MFMA.
// Ps layout [row][64 shorts]; conflict-free P write/read scheme (round 10: 0 conflicts).
__global__ __launch_bounds__(512, 2) void attn(
    const unsigned short* __restrict__ qg, const unsigned short* __restrict__ kg,
    const unsigned short* __restrict__ vtg, const float* __restrict__ mt,
    const unsigned int* __restrict__ mfl, unsigned short* __restrict__ cf)
{
    __shared__ __align__(16) short Ks[2][64*64];
    __shared__ __align__(16) short Vs[2][64*64];
    __shared__ __align__(16) short Ps[128*64];

    const int t = threadIdx.x, lane = t & 63, wv = t >> 6;   // wv 0..7
    const int fr = lane & 15, fg = lane >> 4, frx = fr & 7;
    const int flat = blockIdx.x;
    const int bh = (flat & 7) + ((flat >> 7) << 3);          // XCD-grouped
    const int q0 = ((flat >> 3) & 15) * 128;
    const int b = bh >> 4, h = bh & 15;

    const unsigned short* kgb = kg  + (size_t)bh*SS*HD;
    const unsigned short* vgb = vtg + (size_t)bh*HD*SS;
    const float* mtb = mt + (size_t)b*SS;
    const unsigned int* mfb = mfl + b*32;

    f16x8 qa[2];   // Q[q=q0+16wv+fr][d], pre-scaled by QSCALE
    #pragma unroll
    for (int kc = 0; kc < 2; ++kc)
        qa[kc] = *(const f16x8*)&qg[((size_t)bh*SS + q0 + 16*wv + fr)*HD + kc*32 + fg*8];

    f16x8 onev;
    #pragma unroll
    for (int i = 0; i < 8; ++i) onev[i] = (_Float16)1.0f;

    f32x4 o[4] = {};
    f32x4 oS = {};                        // ones-MFMA row-sum accumulator
    const int pbase = (wv*16 + fr) * 64;
    const int hs = (fr >> 3) * 4;         // row half-slot bit (shorts)

    const int srow = t >> 3, sg = t & 7;    // 512 threads cover 64 rows x 8 granules

    // prologue: stage tile 0
    gld16(kgb + (size_t)srow*HD + sg*8, &Ks[0][srow*64 + sg*8]);
    gld16(vgb + (size_t)srow*SS + sg*8, &Vs[0][srow*64 + sg*8]);
    __syncthreads();

    int cur = 0;
    for (int kt = 0; kt < SS/64; ++kt) {
        const int k0 = kt * 64;
        if (kt + 1 < SS/64) {                 // prefetch next tile
            const int kn = k0 + 64;
            gld16(kgb + (size_t)(kn+srow)*HD + sg*8, &Ks[cur^1][srow*64 + sg*8]);
            gld16(vgb + (size_t)srow*SS + kn + sg*8, &Vs[cur^1][srow*64 + sg*8]);
        }
        const int fl = __builtin_amdgcn_readfirstlane(mfb[kt]);

        // S^T = K Q^T (A=K fragment, B=Q fragment)
        f32x4 sc[4] = {};
        __builtin_amdgcn_s_setprio(1);
        #pragma unroll
        for (int kc = 0; kc < 2; ++kc) {
            #pragma unroll
            for (int nf = 0; nf < 4; ++nf) {
                int gr = (4*kc + fg) ^ frx;
                f16x8 kb = *(const f16x8*)&Ks[cur][(16*nf + fr)*64 + gr*8];
                sc[nf] = __builtin_amdgcn_mfma_f32_16x16x32_f16(kb, qa[kc], sc[nf], 0, 0, 0);
            }
        }
        __builtin_amdgcn_s_setprio(0);

        // P = 2^(s [+ madd]); pack 4 k-adjacent fp16; b64 store at
        // (granule (2nf+(fg>>1))^frx, half (fg&1)^(fr>>3)) -- conflict-free
        if (fl) {                              // unmasked tile (common path)
            #pragma unroll
            for (int nf = 0; nf < 4; ++nf) {
                float p0 = __builtin_amdgcn_exp2f(sc[nf][0]);
                float p1 = __builtin_amdgcn_exp2f(sc[nf][1]);
                float p2 = __builtin_amdgcn_exp2f(sc[nf][2]);
                float p3 = __builtin_amdgcn_exp2f(sc[nf][3]);
                uint2 w; w.x = pkh(p0, p1); w.y = pkh(p2, p3);
                *(uint2*)&Ps[pbase + (((2*nf + (fg >> 1)) ^ frx) * 8) + (4*(fg & 1) ^ hs)] = w;
            }
        } else {
            #pragma unroll
            for (int nf = 0; nf < 4; ++nf) {
                float4 m4 = *(const float4*)&mtb[k0 + 16*nf + 4*fg];
                float p0 = __builtin_amdgcn_exp2f(sc[nf][0] + m4.x);
                float p1 = __builtin_amdgcn_exp2f(sc[nf][1] + m4.y);
                float p2 = __builtin_amdgcn_exp2f(sc[nf][2] + m4.z);
                float p3 = __builtin_amdgcn_exp2f(sc[nf][3] + m4.w);
                uint2 w; w.x = pkh(p0, p1); w.y = pkh(p2, p3);
                *(uint2*)&Ps[pbase + (((2*nf + (fg >> 1)) ^ frx) * 8) + (4*(fg & 1) ^ hs)] = w;
            }
        }

        // O^T += V^T P; row-sum += ones^T P  (wave-private P rows)
        __builtin_amdgcn_s_setprio(1);
        #pragma unroll
        for (int kc = 0; kc < 2; ++kc) {
            int pg = pbase + (((4*kc + fg) ^ frx) * 8);
            union { f16x8 v; uint2 q[2]; } pu;
            pu.q[0] = *(const uint2*)&Ps[pg + hs];         // k-half 0 at slot 0^hs
            pu.q[1] = *(const uint2*)&Ps[pg + (hs ^ 4)];   // k-half 1 at slot 1^hs
            f16x8 pa = pu.v;
            #pragma unroll
            for (int df = 0; df < 4; ++df) {
                f16x8 vb = *(const f16x8*)&Vs[cur][(16*df + fr)*64 + ((4*kc + fg) ^ frx)*8];
                o[df] = __builtin_amdgcn_mfma_f32_16x16x32_f16(vb, pa, o[df], 0, 0, 0);
            }
            oS = __builtin_amdgcn_mfma_f32_16x16x32_f16(onev, pa, oS, 0, 0, 0);
        }
        __builtin_amdgcn_s_setprio(0);
        __syncthreads();   // drains next-tile gld16 (vmcnt) + protects buffers
        cur ^= 1;
    }

    // epilogue: l = sum(p) from ones-MFMA (all rows identical), packed store
    float inv = 1.0f / oS[0];
    size_t base = ((size_t)b*SS + q0 + 16*wv + fr)*HH + h*HD;
    #pragma unroll
    for (int df = 0; df < 4; ++df) {
        uint2 w;
        w.x = pkh(o[df][0]*inv, o[df][1]*inv);
        w.y = pkh(o[df][2]*inv, o[df][3]*inv);
        *(uint2*)&cf[base + 16*df + 4*fg] = w;
    }
}

extern "C" void kernel_launch(void* const* d_in, const int* in_sizes, int n_in,
                              void* d_out, int out_size, void* d_ws, size_t ws_size,
                              hipStream_t stream) {
    const float* x    = (const float*)d_in[0];
    const float* mask = (const float*)d_in[1];
    const float* Wq   = (const float*)d_in[2];
    const float* Wk   = (const float*)d_in[3];
    const float* Wv   = (const float*)d_in[4];
    const float* Wo   = (const float*)d_in[5];
    float* out = (float*)d_out;

    const size_t T = (size_t)MM * HH;            // 4M elements
    unsigned short* xf = (unsigned short*)d_ws;  // 8MB each
    unsigned short* wf = xf + T;                 // [4096][1024]: Wq,Wk,Wv,Wo rows
    unsigned short* qt = wf + T;
    unsigned short* kt = qt + T;
    unsigned short* vt = kt + T;
    float* ctab = (float*)(vt + T);
    float* stab = ctab + SS*32;
    float* mt   = stab + SS*32;                  // additive mask table [BB][SS]
    unsigned int* mfg = (unsigned int*)(mt + BB*SS);   // [BB][32] all-ones flags
    unsigned short* cf = xf;                     // ctx aliases xf (x consumed)

    prep<<<2048, 256, 0, stream>>>(x, mask, Wq, Wk, Wv, Wo, xf, wf, ctab, stab, mt, mfg);
    gemm3<0><<<dim3(MM/128, 3*HH/128), 256, 0, stream>>>(xf, wf, ctab, stab,
                                                         qt, kt, vt, nullptr);
    attn<<<512, 512, 0, stream>>>(qt, kt, vt, mt, mfg, cf);
    gemm3<1><<<dim3(MM/128, HH/128), 256, 0, stream>>>(cf, wf, nullptr, nullptr,
                                                       nullptr, nullptr, nullptr, out);
}

// Round 21
// 112.260 us; speedup vs baseline: 1.1599x; 1.0378x over previous
//
#include <hip/hip_runtime.h>
#include <math.h>

#define BB 2
#define SS 2048
#define HH 1024
#define NH 16
#define HD 64
#define MM (BB*SS)   // 4096

typedef __attribute__((ext_vector_type(8))) _Float16 f16x8;
typedef __attribute__((ext_vector_type(2))) __fp16 hf16x2;
typedef __attribute__((ext_vector_type(4))) float f32x4;

// 0.125 (1/sqrt(64)) * log2(e), folded into Q at the projection epilogue
#define QSCALE 0.18033688011112042f

__device__ __forceinline__ unsigned short f2h(float f) {
    union { _Float16 h; unsigned short u; } c;
    c.h = (_Float16)f;
    return c.u;
}

// pack two floats to fp16x2 (RTZ) -> raw u32
__device__ __forceinline__ unsigned int pkh(float a, float b) {
    union { hf16x2 h; unsigned int u; } c;
    c.h = __builtin_amdgcn_cvt_pkrtz(a, b);
    return c.u;
}

__device__ __forceinline__ void gld16(const void* g, void* s) {
    __builtin_amdgcn_global_load_lds(
        (const __attribute__((address_space(1))) void*)g,
        (__attribute__((address_space(3))) void*)s, 16, 0, 0);
}

// ---------------- prep: cast x/W to fp16 + RoPE/mask tables + mask flags ----------------
__global__ __launch_bounds__(256) void prep(
    const float* __restrict__ x, const float* __restrict__ mask,
    const float* __restrict__ Wq, const float* __restrict__ Wk,
    const float* __restrict__ Wv, const float* __restrict__ Wo,
    unsigned short* __restrict__ xf, unsigned short* __restrict__ wf,
    float* __restrict__ ctab, float* __restrict__ stab, float* __restrict__ mt,
    unsigned int* __restrict__ mflag)
{
    int gtid = blockIdx.x * 256 + threadIdx.x;      // 2048*256 = 524288 threads
    if (gtid < SS * 32) {                            // RoPE table, f64 trig
        int s = gtid >> 5, i = gtid & 31;
        double invf = pow(10000.0, -(double)i / 32.0);
        double a = (double)s * invf;
        ctab[gtid] = (float)cos(a);
        stab[gtid] = (float)sin(a);
    }
    if (gtid < BB * SS) {                            // additive mask table (exp2 domain)
        float mv = mask[gtid];
        mt[gtid] = (1.0f - mv) * (-1.0e38f);
        // per-(b, 64k-tile) all-ones flag: one ballot per wave, lane0 stores
        unsigned long long bal = __ballot(mv == 1.0f);
        if ((threadIdx.x & 63) == 0)
            mflag[gtid >> 6] = (bal == ~0ull) ? 1u : 0u;
    }
    for (int it = gtid; it < 2097152; it += 524288) {   // 2M float4 items
        float4 v; unsigned short* d; size_t off;
        if (it < 1048576) {                              // x: [4096][1024]
            off = (size_t)it * 4;
            v = *(const float4*)(x + off);
            d = xf;
        } else {                                         // W concat rows: Wq,Wk,Wv,Wo
            off = (size_t)(it - 1048576) * 4;
            int row = (int)(off >> 10);
            const float* W = row < 1024 ? Wq : row < 2048 ? Wk : row < 3072 ? Wv : Wo;
            v = *(const float4*)(W + (((size_t)(row & 1023)) << 10) + (off & 1023));
            d = wf;
        }
        *(ushort4*)(d + off) = make_ushort4(f2h(v.x), f2h(v.y), f2h(v.z), f2h(v.w));
    }
}

// ---------------- fp16 MFMA GEMM (128x128 tile, BK=32, dbuf 32KB) — r16 exact ----------------
// LDS tiles [128 rows][4 granules of 16B], 2-bit XOR swizzle (round-5, verified
// 0 conflicts). 2-phase dbuf: STAGE(next) before compute(cur).
// MODE 0 only (QKV): RoPE epilogue; q scaled by QSCALE, plain layout; k swizzled;
// v transposed+swizzled.
template<int MODE>
__global__ __launch_bounds__(256, 3) void gemm3(
    const unsigned short* __restrict__ Axf,
    const unsigned short* __restrict__ Wf,
    const float* __restrict__ ctab, const float* __restrict__ stab,
    unsigned short* __restrict__ qo, unsigned short* __restrict__ ko,
    unsigned short* __restrict__ vo, float* __restrict__ fout)
{
    __shared__ __align__(16) short lsA[2][128*32];
    __shared__ __align__(16) short lsB[2][128*32];

    const int t = threadIdx.x;
    const int m0 = blockIdx.x * 128;
    const int brow0 = (MODE == 0 ? 0 : 3072) + blockIdx.y * 128;
    const int lane = t & 63, wv = t >> 6;
    const int wm = (wv >> 1) * 64, wn = (wv & 1) * 64;
    const int fr = lane & 15, fg = lane >> 4;

    const int srow = t >> 2, pc = t & 3;
    const int scx = (pc ^ ((srow >> 1) & 3)) * 8;     // source col offset (shorts)
    const int lo  = srow * 32 + pc * 8;               // physical dest (shorts)
    const size_t gA0 = (size_t)(m0 + srow) * HH + scx;
    const size_t gA1 = (size_t)(m0 + 64 + srow) * HH + scx;
    const size_t gB0 = (size_t)(brow0 + srow) * HH + scx;
    const size_t gB1 = (size_t)(brow0 + 64 + srow) * HH + scx;

    f32x4 acc[4][4] = {};

#define STAGE(sel, kk) do { \
        gld16(Axf + gA0 + (kk), &lsA[sel][lo]);            \
        gld16(Wf  + gB0 + (kk), &lsB[sel][lo]);            \
        gld16(Axf + gA1 + (kk), &lsA[sel][lo + 64*32]);    \
        gld16(Wf  + gB1 + (kk), &lsB[sel][lo + 64*32]);    \
    } while (0)

    STAGE(0, 0);
    __syncthreads();

    int cur = 0;
    for (int k0 = 0; k0 < HH; k0 += 32) {
        if (k0 + 32 < HH) STAGE(cur ^ 1, k0 + 32);

        f16x8 ah[4], bh[4];
        const int swz = (fg ^ ((fr >> 1) & 3)) * 8;   // swizzled read granule
        #pragma unroll
        for (int mi = 0; mi < 4; ++mi)
            ah[mi] = *(const f16x8*)&lsA[cur][(wm + 16*mi + fr)*32 + swz];
        #pragma unroll
        for (int ni = 0; ni < 4; ++ni)
            bh[ni] = *(const f16x8*)&lsB[cur][(wn + 16*ni + fr)*32 + swz];

        __builtin_amdgcn_s_setprio(1);
        #pragma unroll
        for (int mi = 0; mi < 4; ++mi)
            #pragma unroll
            for (int ni = 0; ni < 4; ++ni)
                acc[mi][ni] = __builtin_amdgcn_mfma_f32_16x16x32_f16(ah[mi], bh[ni], acc[mi][ni], 0, 0, 0);
        __builtin_amdgcn_s_setprio(0);
        __syncthreads();
        cur ^= 1;
    }
#undef STAGE

    if (MODE == 0) {
        const int mat = brow0 >> 10;                 // 0=Q 1=K 2=V
        const int obase = (brow0 & 1023) + wn;       // 64-aligned
        const int h = obase >> 6;
        #pragma unroll
        for (int mi = 0; mi < 4; ++mi)
            #pragma unroll
            for (int rr = 0; rr < 4; ++rr) {
                int m = m0 + wm + 16*mi + 4*fg + rr;
                int b = m >> 11, s = m & (SS - 1);
                float v[4];
                #pragma unroll
                for (int ni = 0; ni < 4; ++ni) v[ni] = acc[mi][ni][rr];
                if (mat < 2) {                        // RoPE on Q,K
                    #pragma unroll
                    for (int ni = 0; ni < 2; ++ni) {
                        int i = 16*ni + fr;
                        float c = ctab[s*32 + i], sn = stab[s*32 + i];
                        float v1 = v[ni], v2 = v[ni + 2];
                        v[ni]     = v1*c - v2*sn;
                        v[ni + 2] = v2*c + v1*sn;
                    }
                }
                if (mat == 0) {                       // fold softmax scale into Q
                    #pragma unroll
                    for (int ni = 0; ni < 4; ++ni) v[ni] *= QSCALE;
                }
                size_t base = ((size_t)(b*NH + h) * SS + s) * HD;
                #pragma unroll
                for (int ni = 0; ni < 4; ++ni) {
                    int d = 16*ni + fr;
                    unsigned short hb = f2h(v[ni]);
                    if (mat == 0)      qo[base + d] = hb;
                    else if (mat == 1) ko[base + (d ^ ((s & 7) << 3))] = hb;
                    else {
                        size_t va = ((size_t)(b*NH + h) * HD + d) * SS
                                  + (s & ~63) + ((s & 63) ^ ((d & 7) << 3));
                        vo[va] = hb;
                    }
                }
            }
    } else {
        const int n0 = blockIdx.y * 128 + wn;
        #pragma unroll
        for (int mi = 0; mi < 4; ++mi)
            #pragma unroll
            for (int rr = 0; rr < 4; ++rr) {
                int m = m0 + wm + 16*mi + 4*fg + rr;
                #pragma unroll
                for (int ni = 0; ni < 4; ++ni)
                    fout[(size_t)m * HH + n0 + 16*ni + fr] = acc[mi][ni][rr];
            }
    }
}

// ---------------- out-projection GEMM: BM=64 x BN=128, BK=32 ----------------
// r20 analysis: the 128x128 out-proj grid was (32,8)=256 blocks = 1 block/CU
// = 4 waves/CU -> every barrier fully latency-exposed (8.6 GF at ~610 TF).
// BM=64 doubles the grid to (64,8)=512 blocks = 2 blocks/CU = 8 waves/CU so
// co-resident blocks overlap each other's barrier drains. Same verified
// swizzle algebra (2-bit XOR, 0 conflicts). 4 waves: wave wv owns all 64 m x
// n-slice [32wv, 32wv+32). LDS 24KB double-buffered.
__global__ __launch_bounds__(256, 2) void gemm_out(
    const unsigned short* __restrict__ Axf,
    const unsigned short* __restrict__ Wf,
    float* __restrict__ fout)
{
    __shared__ __align__(16) short lsA[2][64*32];
    __shared__ __align__(16) short lsB[2][128*32];

    const int t = threadIdx.x;
    const int m0 = blockIdx.x * 64;
    const int brow0 = 3072 + blockIdx.y * 128;        // Wo rows
    const int lane = t & 63, wv = t >> 6;
    const int fr = lane & 15, fg = lane >> 4;

    const int srow = t >> 2, pc = t & 3;              // srow 0..63
    const int scx = (pc ^ ((srow >> 1) & 3)) * 8;     // source col offset (shorts)
    const int lo  = srow * 32 + pc * 8;               // physical dest (shorts)
    const size_t gA0 = (size_t)(m0 + srow) * HH + scx;
    const size_t gB0 = (size_t)(brow0 + srow) * HH + scx;
    const size_t gB1 = (size_t)(brow0 + 64 + srow) * HH + scx;

    f32x4 acc[4][2] = {};

#define STAGEO(sel, kk) do { \
        gld16(Axf + gA0 + (kk), &lsA[sel][lo]);            \
        gld16(Wf  + gB0 + (kk), &lsB[sel][lo]);            \
        gld16(Wf  + gB1 + (kk), &lsB[sel][lo + 64*32]);    \
    } while (0)

    STAGEO(0, 0);
    __syncthreads();

    int cur = 0;
    for (int k0 = 0; k0 < HH; k0 += 32) {
        if (k0 + 32 < HH) STAGEO(cur ^ 1, k0 + 32);

        f16x8 ah[4], bh[2];
        const int swz = (fg ^ ((fr >> 1) & 3)) * 8;   // swizzled read granule
        #pragma unroll
        for (int mi = 0; mi < 4; ++mi)
            ah[mi] = *(const f16x8*)&lsA[cur][(16*mi + fr)*32 + swz];
        #pragma unroll
        for (int ni = 0; ni < 2; ++ni)
            bh[ni] = *(const f16x8*)&lsB[cur][(32*wv + 16*ni + fr)*32 + swz];

        __builtin_amdgcn_s_setprio(1);
        #pragma unroll
        for (int mi = 0; mi < 4; ++mi)
            #pragma unroll
            for (int ni = 0; ni < 2; ++ni)
                acc[mi][ni] = __builtin_amdgcn_mfma_f32_16x16x32_f16(ah[mi], bh[ni], acc[mi][ni], 0, 0, 0);
        __builtin_amdgcn_s_setprio(0);
        __syncthreads();
        cur ^= 1;
    }
#undef STAGEO

    const int n0 = blockIdx.y * 128 + 32 * wv;
    #pragma unroll
    for (int mi = 0; mi < 4; ++mi)
        #pragma unroll
        for (int rr = 0; rr < 4; ++rr) {
            int m = m0 + 16*mi + 4*fg + rr;
            #pragma unroll
            for (int ni = 0; ni < 2; ++ni)
                fout[(size_t)m * HH + n0 + 16*ni + fr] = acc[mi][ni][rr];
        }
}

// ---------------- flash attention, swapped-operand form (r16 exact, 49.6us) ----------------
// 1-D grid 512, XCD-swizzled (K/V L2 locality: FETCH 69.7->12.3MB, round 9).
// S^T = mfma(K,Q); O^T = mfma(V^T,P); row-sum via ones-MFMA.
// Ps layout [row][64 shorts]; conflict-free P write/read scheme (round 10: 0 conflicts).
__global__ __launch_bounds__(512, 2) void attn(
    const unsigned short* __restrict__ qg, const unsigned short* __restrict__ kg,
    const unsigned short* __restrict__ vtg, const float* __restrict__ mt,
    const unsigned int* __restrict__ mfl, unsigned short* __restrict__ cf)
{
    __shared__ __align__(16) short Ks[2][64*64];
    __shared__ __align__(16) short Vs[2][64*64];
    __shared__ __align__(16) short Ps[128*64];

    const int t = threadIdx.x, lane = t & 63, wv = t >> 6;   // wv 0..7
    const int fr = lane & 15, fg = lane >> 4, frx = fr & 7;
    const int flat = blockIdx.x;
    const int bh = (flat & 7) + ((flat >> 7) << 3);          // XCD-grouped
    const int q0 = ((flat >> 3) & 15) * 128;
    const int b = bh >> 4, h = bh & 15;

    const unsigned short* kgb = kg  + (size_t)bh*SS*HD;
    const unsigned short* vgb = vtg + (size_t)bh*HD*SS;
    const float* mtb = mt + (size_t)b*SS;
    const unsigned int* mfb = mfl + b*32;

    f16x8 qa[2];   // Q[q=q0+16wv+fr][d], pre-scaled by QSCALE
    #pragma unroll
    for (int kc = 0; kc < 2; ++kc)
        qa[kc] = *(const f16x8*)&qg[((size_t)bh*SS + q0 + 16*wv + fr)*HD + kc*32 + fg*8];

    f16x8 onev;
    #pragma unroll
    for (int i = 0; i < 8; ++i) onev[i] = (_Float16)1.0f;

    f32x4 o[4] = {};
    f32x4 oS = {};                        // ones-MFMA row-sum accumulator
    const int pbase = (wv*16 + fr) * 64;
    const int hs = (fr >> 3) * 4;         // row half-slot bit (shorts)

    const int srow = t >> 3, sg = t & 7;    // 512 threads cover 64 rows x 8 granules

    // prologue: stage tile 0
    gld16(kgb + (size_t)srow*HD + sg*8, &Ks[0][srow*64 + sg*8]);
    gld16(vgb + (size_t)srow*SS + sg*8, &Vs[0][srow*64 + sg*8]);
    __syncthreads();

    int cur = 0;
    for (int kt = 0; kt < SS/64; ++kt) {
        const int k0 = kt * 64;
        if (kt + 1 < SS/64) {                 // prefetch next tile
            const int kn = k0 + 64;
            gld16(kgb + (size_t)(kn+srow)*HD + sg*8, &Ks[cur^1][srow*64 + sg*8]);
            gld16(vgb + (size_t)srow*SS + kn + sg*8, &Vs[cur^1][srow*64 + sg*8]);
        }
        const int fl = __builtin_amdgcn_readfirstlane(mfb[kt]);

        // S^T = K Q^T (A=K fragment, B=Q fragment)
        f32x4 sc[4] = {};
        __builtin_amdgcn_s_setprio(1);
        #pragma unroll
        for (int kc = 0; kc < 2; ++kc) {
            #pragma unroll
            for (int nf = 0; nf < 4; ++nf) {
                int gr = (4*kc + fg) ^ frx;
                f16x8 kb = *(const f16x8*)&Ks[cur][(16*nf + fr)*64 + gr*8];
                sc[nf] = __builtin_amdgcn_mfma_f32_16x16x32_f16(kb, qa[kc], sc[nf], 0, 0, 0);
            }
        }
        __builtin_amdgcn_s_setprio(0);

        // P = 2^(s [+ madd]); pack 4 k-adjacent fp16; b64 store at
        // (granule (2nf+(fg>>1))^frx, half (fg&1)^(fr>>3)) -- conflict-free
        if (fl) {                              // unmasked tile (common path)
            #pragma unroll
            for (int nf = 0; nf < 4; ++nf) {
                float p0 = __builtin_amdgcn_exp2f(sc[nf][0]);
                float p1 = __builtin_amdgcn_exp2f(sc[nf][1]);
                float p2 = __builtin_amdgcn_exp2f(sc[nf][2]);
                float p3 = __builtin_amdgcn_exp2f(sc[nf][3]);
                uint2 w; w.x = pkh(p0, p1); w.y = pkh(p2, p3);
                *(uint2*)&Ps[pbase + (((2*nf + (fg >> 1)) ^ frx) * 8) + (4*(fg & 1) ^ hs)] = w;
            }
        } else {
            #pragma unroll
            for (int nf = 0; nf < 4; ++nf) {
                float4 m4 = *(const float4*)&mtb[k0 + 16*nf + 4*fg];
                float p0 = __builtin_amdgcn_exp2f(sc[nf][0] + m4.x);
                float p1 = __builtin_amdgcn_exp2f(sc[nf][1] + m4.y);
                float p2 = __builtin_amdgcn_exp2f(sc[nf][2] + m4.z);
                float p3 = __builtin_amdgcn_exp2f(sc[nf][3] + m4.w);
                uint2 w; w.x = pkh(p0, p1); w.y = pkh(p2, p3);
                *(uint2*)&Ps[pbase + (((2*nf + (fg >> 1)) ^ frx) * 8) + (4*(fg & 1) ^ hs)] = w;
            }
        }

        // O^T += V^T P; row-sum += ones^T P  (wave-private P rows)
        __builtin_amdgcn_s_setprio(1);
        #pragma unroll
        for (int kc = 0; kc < 2; ++kc) {
            int pg = pbase + (((4*kc + fg) ^ frx) * 8);
            union { f16x8 v; uint2 q[2]; } pu;
            pu.q[0] = *(const uint2*)&Ps[pg + hs];         // k-half 0 at slot 0^hs
            pu.q[1] = *(const uint2*)&Ps[pg + (hs ^ 4)];   // k-half 1 at slot 1^hs
            f16x8 pa = pu.v;
            #pragma unroll
            for (int df = 0; df < 4; ++df) {
                f16x8 vb = *(const f16x8*)&Vs[cur][(16*df + fr)*64 + ((4*kc + fg) ^ frx)*8];
                o[df] = __builtin_amdgcn_mfma_f32_16x16x32_f16(vb, pa, o[df], 0, 0, 0);
            }
            oS = __builtin_amdgcn_mfma_f32_16x16x32_f16(onev, pa, oS, 0, 0, 0);
        }
        __builtin_amdgcn_s_setprio(0);
        __syncthreads();   // drains next-tile gld16 (vmcnt) + protects buffers
        cur ^= 1;
    }

    // epilogue: l = sum(p) from ones-MFMA (all rows identical), packed store
    float inv = 1.0f / oS[0];
    size_t base = ((size_t)b*SS + q0 + 16*wv + fr)*HH + h*HD;
    #pragma unroll
    for (int df = 0; df < 4; ++df) {
        uint2 w;
        w.x = pkh(o[df][0]*inv, o[df][1]*inv);
        w.y = pkh(o[df][2]*inv, o[df][3]*inv);
        *(uint2*)&cf[base + 16*df + 4*fg] = w;
    }
}

extern "C" void kernel_launch(void* const* d_in, const int* in_sizes, int n_in,
                              void* d_out, int out_size, void* d_ws, size_t ws_size,
                              hipStream_t stream) {
    const float* x    = (const float*)d_in[0];
    const float* mask = (const float*)d_in[1];
    const float* Wq   = (const float*)d_in[2];
    const float* Wk   = (const float*)d_in[3];
    const float* Wv   = (const float*)d_in[4];
    const float* Wo   = (const float*)d_in[5];
    float* out = (float*)d_out;

    const size_t T = (size_t)MM * HH;            // 4M elements
    unsigned short* xf = (unsigned short*)d_ws;  // 8MB each
    unsigned short* wf = xf + T;                 // [4096][1024]: Wq,Wk,Wv,Wo rows
    unsigned short* qt = wf + T;
    unsigned short* kt = qt + T;
    unsigned short* vt = kt + T;
    float* ctab = (float*)(vt + T);
    float* stab = ctab + SS*32;
    float* mt   = stab + SS*32;                  // additive mask table [BB][SS]
    unsigned int* mfg = (unsigned int*)(mt + BB*SS);   // [BB][32] all-ones flags
    unsigned short* cf = xf;                     // ctx aliases xf (x consumed)

    prep<<<2048, 256, 0, stream>>>(x, mask, Wq, Wk, Wv, Wo, xf, wf, ctab, stab, mt, mfg);
    gemm3<0><<<dim3(MM/128, 3*HH/128), 256, 0, stream>>>(xf, wf, ctab, stab,
                                                         qt, kt, vt, nullptr);
    attn<<<512, 512, 0, stream>>>(qt, kt, vt, mt, mfg, cf);
    gemm_out<<<dim3(MM/64, HH/128), 256, 0, stream>>>(cf, wf, out);
}

// Round 22
// 107.006 us; speedup vs baseline: 1.2169x; 1.0491x over previous
//
#include <hip/hip_runtime.h>
#include <math.h>

#define BB 2
#define SS 2048
#define HH 1024
#define NH 16
#define HD 64
#define MM (BB*SS)   // 4096

typedef __attribute__((ext_vector_type(8))) _Float16 f16x8;
typedef __attribute__((ext_vector_type(2))) __fp16 hf16x2;
typedef __attribute__((ext_vector_type(4))) float f32x4;

// 0.125 (1/sqrt(64)) * log2(e), folded into Q at the projection epilogue
#define QSCALE 0.18033688011112042f

__device__ __forceinline__ unsigned short f2h(float f) {
    union { _Float16 h; unsigned short u; } c;
    c.h = (_Float16)f;
    return c.u;
}

// pack two floats to fp16x2 (RTZ) -> raw u32
__device__ __forceinline__ unsigned int pkh(float a, float b) {
    union { hf16x2 h; unsigned int u; } c;
    c.h = __builtin_amdgcn_cvt_pkrtz(a, b);
    return c.u;
}

__device__ __forceinline__ void gld16(const void* g, void* s) {
    __builtin_amdgcn_global_load_lds(
        (const __attribute__((address_space(1))) void*)g,
        (__attribute__((address_space(3))) void*)s, 16, 0, 0);
}

// ---------------- prep: cast x/W to fp16 + RoPE/mask tables + mask flags ----------------
__global__ __launch_bounds__(256) void prep(
    const float* __restrict__ x, const float* __restrict__ mask,
    const float* __restrict__ Wq, const float* __restrict__ Wk,
    const float* __restrict__ Wv, const float* __restrict__ Wo,
    unsigned short* __restrict__ xf, unsigned short* __restrict__ wf,
    float* __restrict__ ctab, float* __restrict__ stab, float* __restrict__ mt,
    unsigned int* __restrict__ mflag)
{
    int gtid = blockIdx.x * 256 + threadIdx.x;      // 2048*256 = 524288 threads
    if (gtid < SS * 32) {                            // RoPE table, f64 trig
        int s = gtid >> 5, i = gtid & 31;
        double invf = pow(10000.0, -(double)i / 32.0);
        double a = (double)s * invf;
        ctab[gtid] = (float)cos(a);
        stab[gtid] = (float)sin(a);
    }
    if (gtid < BB * SS) {                            // additive mask table (exp2 domain)
        float mv = mask[gtid];
        mt[gtid] = (1.0f - mv) * (-1.0e38f);
        // per-(b, 64k-tile) all-ones flag: one ballot per wave, lane0 stores
        unsigned long long bal = __ballot(mv == 1.0f);
        if ((threadIdx.x & 63) == 0)
            mflag[gtid >> 6] = (bal == ~0ull) ? 1u : 0u;
    }
    for (int it = gtid; it < 2097152; it += 524288) {   // 2M float4 items
        float4 v; unsigned short* d; size_t off;
        if (it < 1048576) {                              // x: [4096][1024]
            off = (size_t)it * 4;
            v = *(const float4*)(x + off);
            d = xf;
        } else {                                         // W concat rows: Wq,Wk,Wv,Wo
            off = (size_t)(it - 1048576) * 4;
            int row = (int)(off >> 10);
            const float* W = row < 1024 ? Wq : row < 2048 ? Wk : row < 3072 ? Wv : Wo;
            v = *(const float4*)(W + (((size_t)(row & 1023)) << 10) + (off & 1023));
            d = wf;
        }
        *(ushort4*)(d + off) = make_ushort4(f2h(v.x), f2h(v.y), f2h(v.z), f2h(v.w));
    }
}

// ---------------- fp16 MFMA GEMM (128x128 tile, BK=32, dbuf 32KB) ----------------
// LDS tiles [128 rows][4 granules of 16B], 2-bit XOR swizzle (round-5, verified
// 0 conflicts). 2-phase dbuf: STAGE(next) before compute(cur).
// MODE 0 (QKV): RoPE epilogue; q scaled by QSCALE plain; k swizzled.
// NEW (r22): V blocks (mat==2) swap MFMA operand roles (A=W-tile, B=x-tile) so
// the output fragment col = fr = s -> the V^T store's 16 fr-lanes write 16
// CONSECUTIVE s (two 16B-dense chunks after the d-XOR swizzle) instead of 16
// scattered 2B singles at 4KB stride (8x fewer L2 write txns). Stored byte
// layout identical (same swizzle formula) -> attn unchanged. Math identical:
// C[d][s] = sum_k W[d,k] x[s,k], same MFMA accumulation order.
template<int MODE>
__global__ __launch_bounds__(256, 3) void gemm3(
    const unsigned short* __restrict__ Axf,
    const unsigned short* __restrict__ Wf,
    const float* __restrict__ ctab, const float* __restrict__ stab,
    unsigned short* __restrict__ qo, unsigned short* __restrict__ ko,
    unsigned short* __restrict__ vo, float* __restrict__ fout)
{
    __shared__ __align__(16) short lsA[2][128*32];
    __shared__ __align__(16) short lsB[2][128*32];

    const int t = threadIdx.x;
    const int m0 = blockIdx.x * 128;
    const int brow0 = (MODE == 0 ? 0 : 3072) + blockIdx.y * 128;
    const int mat = (MODE == 0) ? (brow0 >> 10) : 3;     // 0=Q 1=K 2=V 3=out
    const bool swp = (mat == 2);                          // V: swap operand roles
    const int lane = t & 63, wv = t >> 6;
    const int wm = (wv >> 1) * 64, wn = (wv & 1) * 64;
    const int fr = lane & 15, fg = lane >> 4;

    const int srow = t >> 2, pc = t & 3;
    const int scx = (pc ^ ((srow >> 1) & 3)) * 8;     // source col offset (shorts)
    const int lo  = srow * 32 + pc * 8;               // physical dest (shorts)
    const size_t gA0 = (size_t)(m0 + srow) * HH + scx;
    const size_t gA1 = (size_t)(m0 + 64 + srow) * HH + scx;
    const size_t gB0 = (size_t)(brow0 + srow) * HH + scx;
    const size_t gB1 = (size_t)(brow0 + 64 + srow) * HH + scx;

    f32x4 acc[4][4] = {};

#define STAGE(sel, kk) do { \
        gld16(Axf + gA0 + (kk), &lsA[sel][lo]);            \
        gld16(Wf  + gB0 + (kk), &lsB[sel][lo]);            \
        gld16(Axf + gA1 + (kk), &lsA[sel][lo + 64*32]);    \
        gld16(Wf  + gB1 + (kk), &lsB[sel][lo + 64*32]);    \
    } while (0)

    STAGE(0, 0);
    __syncthreads();

    // fragment sources: normal (A=x, B=W); V blocks swapped (A=W, B=x)
    const short (*tileM)[128*32] = swp ? lsB : lsA;
    const short (*tileN)[128*32] = swp ? lsA : lsB;

    int cur = 0;
    for (int k0 = 0; k0 < HH; k0 += 32) {
        if (k0 + 32 < HH) STAGE(cur ^ 1, k0 + 32);

        f16x8 ah[4], bh[4];
        const int swz = (fg ^ ((fr >> 1) & 3)) * 8;   // swizzled read granule
        #pragma unroll
        for (int mi = 0; mi < 4; ++mi)
            ah[mi] = *(const f16x8*)&tileM[cur][(wm + 16*mi + fr)*32 + swz];
        #pragma unroll
        for (int ni = 0; ni < 4; ++ni)
            bh[ni] = *(const f16x8*)&tileN[cur][(wn + 16*ni + fr)*32 + swz];

        __builtin_amdgcn_s_setprio(1);
        #pragma unroll
        for (int mi = 0; mi < 4; ++mi)
            #pragma unroll
            for (int ni = 0; ni < 4; ++ni)
                acc[mi][ni] = __builtin_amdgcn_mfma_f32_16x16x32_f16(ah[mi], bh[ni], acc[mi][ni], 0, 0, 0);
        __builtin_amdgcn_s_setprio(0);
        __syncthreads();
        cur ^= 1;
    }
#undef STAGE

    if (MODE == 0) {
        if (swp) {
            // V (swapped): acc[mi] rows = W-rows (output-dim), acc[ni] cols = x-rows (s)
            #pragma unroll
            for (int mi = 0; mi < 4; ++mi)
                #pragma unroll
                for (int rr = 0; rr < 4; ++rr) {
                    int orow = (brow0 & 1023) + wm + 16*mi + 4*fg + rr;
                    int h = orow >> 6, d = orow & 63;
                    #pragma unroll
                    for (int ni = 0; ni < 4; ++ni) {
                        int scol = m0 + wn + 16*ni + fr;
                        int b2 = scol >> 11, s = scol & (SS - 1);
                        size_t va = ((size_t)(b2*NH + h) * HD + d) * SS
                                  + (s & ~63) + ((s & 63) ^ ((d & 7) << 3));
                        vo[va] = f2h(acc[mi][ni][rr]);
                    }
                }
        } else {
            const int obase = (brow0 & 1023) + wn;       // 64-aligned
            const int h = obase >> 6;
            #pragma unroll
            for (int mi = 0; mi < 4; ++mi)
                #pragma unroll
                for (int rr = 0; rr < 4; ++rr) {
                    int m = m0 + wm + 16*mi + 4*fg + rr;
                    int b = m >> 11, s = m & (SS - 1);
                    float v[4];
                    #pragma unroll
                    for (int ni = 0; ni < 4; ++ni) v[ni] = acc[mi][ni][rr];
                    // RoPE on Q,K
                    #pragma unroll
                    for (int ni = 0; ni < 2; ++ni) {
                        int i = 16*ni + fr;
                        float c = ctab[s*32 + i], sn = stab[s*32 + i];
                        float v1 = v[ni], v2 = v[ni + 2];
                        v[ni]     = v1*c - v2*sn;
                        v[ni + 2] = v2*c + v1*sn;
                    }
                    if (mat == 0) {                       // fold softmax scale into Q
                        #pragma unroll
                        for (int ni = 0; ni < 4; ++ni) v[ni] *= QSCALE;
                    }
                    size_t base = ((size_t)(b*NH + h) * SS + s) * HD;
                    #pragma unroll
                    for (int ni = 0; ni < 4; ++ni) {
                        int d = 16*ni + fr;
                        unsigned short hb = f2h(v[ni]);
                        if (mat == 0) qo[base + d] = hb;
                        else          ko[base + (d ^ ((s & 7) << 3))] = hb;
                    }
                }
        }
    } else {
        const int n0 = blockIdx.y * 128 + wn;
        #pragma unroll
        for (int mi = 0; mi < 4; ++mi)
            #pragma unroll
            for (int rr = 0; rr < 4; ++rr) {
                int m = m0 + wm + 16*mi + 4*fg + rr;
                #pragma unroll
                for (int ni = 0; ni < 4; ++ni)
                    fout[(size_t)m * HH + n0 + 16*ni + fr] = acc[mi][ni][rr];
            }
    }
}

// ---------------- out-projection GEMM: BM=64 x BN=128, BK=32 (r21, verified) ----------------
__global__ __launch_bounds__(256, 2) void gemm_out(
    const unsigned short* __restrict__ Axf,
    const unsigned short* __restrict__ Wf,
    float* __restrict__ fout)
{
    __shared__ __align__(16) short lsA[2][64*32];
    __shared__ __align__(16) short lsB[2][128*32];

    const int t = threadIdx.x;
    const int m0 = blockIdx.x * 64;
    const int brow0 = 3072 + blockIdx.y * 128;        // Wo rows
    const int lane = t & 63, wv = t >> 6;
    const int fr = lane & 15, fg = lane >> 4;

    const int srow = t >> 2, pc = t & 3;              // srow 0..63
    const int scx = (pc ^ ((srow >> 1) & 3)) * 8;     // source col offset (shorts)
    const int lo  = srow * 32 + pc * 8;               // physical dest (shorts)
    const size_t gA0 = (size_t)(m0 + srow) * HH + scx;
    const size_t gB0 = (size_t)(brow0 + srow) * HH + scx;
    const size_t gB1 = (size_t)(brow0 + 64 + srow) * HH + scx;

    f32x4 acc[4][2] = {};

#define STAGEO(sel, kk) do { \
        gld16(Axf + gA0 + (kk), &lsA[sel][lo]);            \
        gld16(Wf  + gB0 + (kk), &lsB[sel][lo]);            \
        gld16(Wf  + gB1 + (kk), &lsB[sel][lo + 64*32]);    \
    } while (0)

    STAGEO(0, 0);
    __syncthreads();

    int cur = 0;
    for (int k0 = 0; k0 < HH; k0 += 32) {
        if (k0 + 32 < HH) STAGEO(cur ^ 1, k0 + 32);

        f16x8 ah[4], bh[2];
        const int swz = (fg ^ ((fr >> 1) & 3)) * 8;   // swizzled read granule
        #pragma unroll
        for (int mi = 0; mi < 4; ++mi)
            ah[mi] = *(const f16x8*)&lsA[cur][(16*mi + fr)*32 + swz];
        #pragma unroll
        for (int ni = 0; ni < 2; ++ni)
            bh[ni] = *(const f16x8*)&lsB[cur][(32*wv + 16*ni + fr)*32 + swz];

        __builtin_amdgcn_s_setprio(1);
        #pragma unroll
        for (int mi = 0; mi < 4; ++mi)
            #pragma unroll
            for (int ni = 0; ni < 2; ++ni)
                acc[mi][ni] = __builtin_amdgcn_mfma_f32_16x16x32_f16(ah[mi], bh[ni], acc[mi][ni], 0, 0, 0);
        __builtin_amdgcn_s_setprio(0);
        __syncthreads();
        cur ^= 1;
    }
#undef STAGEO

    const int n0 = blockIdx.y * 128 + 32 * wv;
    #pragma unroll
    for (int mi = 0; mi < 4; ++mi)
        #pragma unroll
        for (int rr = 0; rr < 4; ++rr) {
            int m = m0 + 16*mi + 4*fg + rr;
            #pragma unroll
            for (int ni = 0; ni < 2; ++ni)
                fout[(size_t)m * HH + n0 + 16*ni + fr] = acc[mi][ni][rr];
        }
}

// ---------------- flash attention, swapped-operand form (r16 exact, 49.6us) ----------------
// 1-D grid 512, XCD-swizzled (K/V L2 locality: FETCH 69.7->12.3MB, round 9).
// S^T = mfma(K,Q); O^T = mfma(V^T,P); row-sum via ones-MFMA.
// Ps layout [row][64 shorts]; conflict-free P write/read scheme (round 10: 0 conflicts).
__global__ __launch_bounds__(512, 2) void attn(
    const unsigned short* __restrict__ qg, const unsigned short* __restrict__ kg,
    const unsigned short* __restrict__ vtg, const float* __restrict__ mt,
    const unsigned int* __restrict__ mfl, unsigned short* __restrict__ cf)
{
    __shared__ __align__(16) short Ks[2][64*64];
    __shared__ __align__(16) short Vs[2][64*64];
    __shared__ __align__(16) short Ps[128*64];

    const int t = threadIdx.x, lane = t & 63, wv = t >> 6;   // wv 0..7
    const int fr = lane & 15, fg = lane >> 4, frx = fr & 7;
    const int flat = blockIdx.x;
    const int bh = (flat & 7) + ((flat >> 7) << 3);          // XCD-grouped
    const int q0 = ((flat >> 3) & 15) * 128;
    const int b = bh >> 4, h = bh & 15;

    const unsigned short* kgb = kg  + (size_t)bh*SS*HD;
    const unsigned short* vgb = vtg + (size_t)bh*HD*SS;
    const float* mtb = mt + (size_t)b*SS;
    const unsigned int* mfb = mfl + b*32;

    f16x8 qa[2];   // Q[q=q0+16wv+fr][d], pre-scaled by QSCALE
    #pragma unroll
    for (int kc = 0; kc < 2; ++kc)
        qa[kc] = *(const f16x8*)&qg[((size_t)bh*SS + q0 + 16*wv + fr)*HD + kc*32 + fg*8];

    f16x8 onev;
    #pragma unroll
    for (int i = 0; i < 8; ++i) onev[i] = (_Float16)1.0f;

    f32x4 o[4] = {};
    f32x4 oS = {};                        // ones-MFMA row-sum accumulator
    const int pbase = (wv*16 + fr) * 64;
    const int hs = (fr >> 3) * 4;         // row half-slot bit (shorts)

    const int srow = t >> 3, sg = t & 7;    // 512 threads cover 64 rows x 8 granules

    // prologue: stage tile 0
    gld16(kgb + (size_t)srow*HD + sg*8, &Ks[0][srow*64 + sg*8]);
    gld16(vgb + (size_t)srow*SS + sg*8, &Vs[0][srow*64 + sg*8]);
    __syncthreads();

    int cur = 0;
    for (int kt = 0; kt < SS/64; ++kt) {
        const int k0 = kt * 64;
        if (kt + 1 < SS/64) {                 // prefetch next tile
            const int kn = k0 + 64;
            gld16(kgb + (size_t)(kn+srow)*HD + sg*8, &Ks[cur^1][srow*64 + sg*8]);
            gld16(vgb + (size_t)srow*SS + kn + sg*8, &Vs[cur^1][srow*64 + sg*8]);
        }
        const int fl = __builtin_amdgcn_readfirstlane(mfb[kt]);

        // S^T = K Q^T (A=K fragment, B=Q fragment)
        f32x4 sc[4] = {};
        __builtin_amdgcn_s_setprio(1);
        #pragma unroll
        for (int kc = 0; kc < 2; ++kc) {
            #pragma unroll
            for (int nf = 0; nf < 4; ++nf) {
                int gr = (4*kc + fg) ^ frx;
                f16x8 kb = *(const f16x8*)&Ks[cur][(16*nf + fr)*64 + gr*8];
                sc[nf] = __builtin_amdgcn_mfma_f32_16x16x32_f16(kb, qa[kc], sc[nf], 0, 0, 0);
            }
        }
        __builtin_amdgcn_s_setprio(0);

        // P = 2^(s [+ madd]); pack 4 k-adjacent fp16; b64 store at
        // (granule (2nf+(fg>>1))^frx, half (fg&1)^(fr>>3)) -- conflict-free
        if (fl) {                              // unmasked tile (common path)
            #pragma unroll
            for (int nf = 0; nf < 4; ++nf) {
                float p0 = __builtin_amdgcn_exp2f(sc[nf][0]);
                float p1 = __builtin_amdgcn_exp2f(sc[nf][1]);
                float p2 = __builtin_amdgcn_exp2f(sc[nf][2]);
                float p3 = __builtin_amdgcn_exp2f(sc[nf][3]);
                uint2 w; w.x = pkh(p0, p1); w.y = pkh(p2, p3);
                *(uint2*)&Ps[pbase + (((2*nf + (fg >> 1)) ^ frx) * 8) + (4*(fg & 1) ^ hs)] = w;
            }
        } else {
            #pragma unroll
            for (int nf = 0; nf < 4; ++nf) {
                float4 m4 = *(const float4*)&mtb[k0 + 16*nf + 4*fg];
                float p0 = __builtin_amdgcn_exp2f(sc[nf][0] + m4.x);
                float p1 = __builtin_amdgcn_exp2f(sc[nf][1] + m4.y);
                float p2 = __builtin_amdgcn_exp2f(sc[nf][2] + m4.z);
                float p3 = __builtin_amdgcn_exp2f(sc[nf][3] + m4.w);
                uint2 w; w.x = pkh(p0, p1); w.y = pkh(p2, p3);
                *(uint2*)&Ps[pbase + (((2*nf + (fg >> 1)) ^ frx) * 8) + (4*(fg & 1) ^ hs)] = w;
            }
        }

        // O^T += V^T P; row-sum += ones^T P  (wave-private P rows)
        __builtin_amdgcn_s_setprio(1);
        #pragma unroll
        for (int kc = 0; kc < 2; ++kc) {
            int pg = pbase + (((4*kc + fg) ^ frx) * 8);
            union { f16x8 v; uint2 q[2]; } pu;
            pu.q[0] = *(const uint2*)&Ps[pg + hs];         // k-half 0 at slot 0^hs
            pu.q[1] = *(const uint2*)&Ps[pg + (hs ^ 4)];   // k-half 1 at slot 1^hs
            f16x8 pa = pu.v;
            #pragma unroll
            for (int df = 0; df < 4; ++df) {
                f16x8 vb = *(const f16x8*)&Vs[cur][(16*df + fr)*64 + ((4*kc + fg) ^ frx)*8];
                o[df] = __builtin_amdgcn_mfma_f32_16x16x32_f16(vb, pa, o[df], 0, 0, 0);
            }
            oS = __builtin_amdgcn_mfma_f32_16x16x32_f16(onev, pa, oS, 0, 0, 0);
        }
        __builtin_amdgcn_s_setprio(0);
        __syncthreads();   // drains next-tile gld16 (vmcnt) + protects buffers
        cur ^= 1;
    }

    // epilogue: l = sum(p) from ones-MFMA (all rows identical), packed store
    float inv = 1.0f / oS[0];
    size_t base = ((size_t)b*SS + q0 + 16*wv + fr)*HH + h*HD;
    #pragma unroll
    for (int df = 0; df < 4; ++df) {
        uint2 w;
        w.x = pkh(o[df][0]*inv, o[df][1]*inv);
        w.y = pkh(o[df][2]*inv, o[df][3]*inv);
        *(uint2*)&cf[base + 16*df + 4*fg] = w;
    }
}

extern "C" void kernel_launch(void* const* d_in, const int* in_sizes, int n_in,
                              void* d_out, int out_size, void* d_ws, size_t ws_size,
                              hipStream_t stream) {
    const float* x    = (const float*)d_in[0];
    const float* mask = (const float*)d_in[1];
    const float* Wq   = (const float*)d_in[2];
    const float* Wk   = (const float*)d_in[3];
    const float* Wv   = (const float*)d_in[4];
    const float* Wo   = (const float*)d_in[5];
    float* out = (float*)d_out;

    const size_t T = (size_t)MM * HH;            // 4M elements
    unsigned short* xf = (unsigned short*)d_ws;  // 8MB each
    unsigned short* wf = xf + T;                 // [4096][1024]: Wq,Wk,Wv,Wo rows
    unsigned short* qt = wf + T;
    unsigned short* kt = qt + T;
    unsigned short* vt = kt + T;
    float* ctab = (float*)(vt + T);
    float* stab = ctab + SS*32;
    float* mt   = stab + SS*32;                  // additive mask table [BB][SS]
    unsigned int* mfg = (unsigned int*)(mt + BB*SS);   // [BB][32] all-ones flags
    unsigned short* cf = xf;                     // ctx aliases xf (x consumed)

    prep<<<2048, 256, 0, stream>>>(x, mask, Wq, Wk, Wv, Wo, xf, wf, ctab, stab, mt, mfg);
    gemm3<0><<<dim3(MM/128, 3*HH/128), 256, 0, stream>>>(xf, wf, ctab, stab,
                                                         qt, kt, vt, nullptr);
    attn<<<512, 512, 0, stream>>>(qt, kt, vt, mt, mfg, cf);
    gemm_out<<<dim3(MM/64, HH/128), 256, 0, stream>>>(cf, wf, out);
}